// Round 11
// baseline (136.912 us; speedup 1.0000x reference)
//
#include <hip/hip_runtime.h>
#include <hip/hip_fp16.h>
#include <cstdint>
#include <cstddef>

// Problem constants: B=8, T=4096, D=512, H=512
constexpr int Bb = 8, Tt = 4096, Dd = 512, Hh = 512;
constexpr int Mm = Bb * Tt;          // 32768 rows
constexpr int CHUNKS = 128;
constexpr int CLEN = Tt / CHUNKS;    // 32

typedef short short8 __attribute__((ext_vector_type(8)));
typedef float f32x4 __attribute__((ext_vector_type(4)));

__device__ inline void gload_lds16(const void* g, void* lds) {
  __builtin_amdgcn_global_load_lds(
      (const __attribute__((address_space(1))) unsigned int*)g,
      (__attribute__((address_space(3))) unsigned int*)lds,
      16, 0, 0);
}

__device__ inline unsigned short bf16_rne(float f) {
  unsigned int u = __float_as_uint(f);
  unsigned int r = (u + 0x7FFFu + ((u >> 16) & 1u)) >> 16;
  return (unsigned short)r;
}
__device__ inline float bf16_tof(unsigned short u) {
  return __uint_as_float(((unsigned int)u) << 16);
}
__device__ inline uint2 pack4_bf16(const float* p) {
  uint2 hv;
  hv.x = (unsigned)bf16_rne(p[0]) | ((unsigned)bf16_rne(p[1]) << 16);
  hv.y = (unsigned)bf16_rne(p[2]) | ((unsigned)bf16_rne(p[3]) << 16);
  return hv;
}

// Merged prep: blocks [0,16384) convert x -> xb; blocks [16384,16896) W -> Wc.
__global__ __launch_bounds__(256) void prep_all(
    const float* __restrict__ x, const float* __restrict__ Wz,
    const float* __restrict__ Wh, unsigned short* __restrict__ xb,
    unsigned short* __restrict__ Wc) {
  int bid = blockIdx.x;
  if (bid < 16384) {
    size_t i = (size_t)bid * 256 + threadIdx.x;
    float4 w = *(const float4*)(x + i * 4);
    *(uint2*)(xb + i * 4) = pack4_bf16((const float*)&w);
  } else {
    int j = (bid - 16384) * 256 + threadIdx.x;
    const float* src = (j < 65536) ? (Wz + (size_t)j * 4)
                                   : (Wh + (size_t)(j - 65536) * 4);
    float4 w = *(const float4*)src;
    *(uint2*)(Wc + (size_t)j * 4) = pack4_bf16((const float*)&w);
  }
}

__global__ __launch_bounds__(256) void prep_w(
    const float* __restrict__ Wz, const float* __restrict__ Wh,
    unsigned short* __restrict__ Wc) {
  int j = blockIdx.x * 256 + threadIdx.x;
  const float* src = (j < 65536) ? (Wz + (size_t)j * 4)
                                 : (Wh + (size_t)(j - 65536) * 4);
  float4 w = *(const float4*)src;
  *(uint2*)(Wc + (size_t)j * 4) = pack4_bf16((const float*)&w);
}

__device__ inline void gates_c(float kv, float pv, float& a, float& v) {
  a = 1.f / (1.f + __expf(kv));
  float z = 1.f - a;
  float g = (pv >= 0.f) ? (pv + 0.5f) : 1.f / (1.f + __expf(-pv));
  v = z * g;
}

#define SB() __builtin_amdgcn_sched_barrier(0)
#define BAR() do { SB(); __builtin_amdgcn_s_barrier(); SB(); } while (0)

// m201-style 8-phase fused dual-GEMM.
// Block: 256 rows x (128h x {Wz,Wh}) = 256x256 virtual tile, 8 waves (2M x 4N),
// wave = 128 rows x 64 vcols; q<2 -> Wz pipe (k preact, ak), q>=2 -> Wh (ph, ap).
// LDS 128KB: 2 dbuf x 2 half x {A[128][64] 16KB + B[128][64] 16KB}.
// half hf: A rows hf*128.., B = (hf==0 ? Wz : Wh) panel.
// 4 phases/K-tile, vmcnt(4) counted once per tile boundary, T2 swizzle, T5 prio.
__global__ __launch_bounds__(512, 2) void gemm8(
    const unsigned short* __restrict__ xb, const unsigned short* __restrict__ Wc,
    const float* __restrict__ bz, const float* __restrict__ bh,
    unsigned int* __restrict__ av,
    float* __restrict__ aggA, float* __restrict__ aggH) {
  __shared__ __align__(16) char smem[131072];

  const int tid = threadIdx.x;
  const int lane = tid & 63, wid = tid >> 6;
  const int bm = blockIdx.x >> 2, hn = blockIdx.x & 3;
  const int row0 = bm * 256, h0 = hn * 128;

  const int m = wid >> 2;        // row half (0/1)
  const int q = wid & 3;         // 0,1 = Wz/ak ; 2,3 = Wh/ap
  const int fr = lane & 15, kg = lane >> 4, fr7 = lane & 7;
  const int r8 = lane >> 3;
  const int c8 = ((lane & 7) ^ r8) * 8;   // pre-swizzled global col slot

  f32x4 acc[8][4];
#pragma unroll
  for (int i = 0; i < 8; ++i)
#pragma unroll
    for (int j = 0; j < 4; ++j) acc[i][j] = (f32x4)0.f;

  // stage half hf of K-tile T (4 gloads/wave: A x2, B x2)
#define STAGEH(T, HF)                                                          \
  {                                                                            \
    const int d_ = (T) & 1, kk_ = (T) * 64;                                    \
    char* base_ = smem + d_ * 65536 + (HF) * 32768;                            \
    _Pragma("unroll")                                                          \
    for (int r_ = 0; r_ < 2; ++r_) {                                           \
      int st_ = r_ * 64 + wid * 8;                                             \
      gload_lds16(xb + (size_t)(row0 + (HF) * 128 + st_ + r8) * Dd + kk_ + c8, \
                  base_ + st_ * 128);                                          \
    }                                                                          \
    _Pragma("unroll")                                                          \
    for (int r_ = 0; r_ < 2; ++r_) {                                           \
      int st_ = r_ * 64 + wid * 8;                                             \
      gload_lds16(Wc + (size_t)((HF) * 512 + h0 + st_ + r8) * Dd + kk_ + c8,   \
                  base_ + 16384 + st_ * 128);                                  \
    }                                                                          \
  }

  // Prologue: H(0,0), H(0,1), H(1,0)  (oldest-first for vmcnt counting)
  STAGEH(0, 0); STAGEH(0, 1); STAGEH(1, 0);

#pragma unroll
  for (int t = 0; t < 8; ++t) {
    // tile boundary: all waves' H(t,*) loads done (keep H(t+1,0)'s 4 in flight)
    if (t < 7) { asm volatile("s_waitcnt vmcnt(4)" ::: "memory"); }
    else       { asm volatile("s_waitcnt vmcnt(0)" ::: "memory"); }
    BAR();

    const int d = t & 1;
    const unsigned short* Ab = (const unsigned short*)(smem + d * 65536 + m * 32768);
    const unsigned short* Bbp = (const unsigned short*)(smem + d * 65536 + (q >> 1) * 32768 + 16384);
    const int qh = q & 1;

    short8 fa[4][2], fb[4][2];

    // ---- phase 0: read fa(mi0-3), fb(ni0-1); stage H(t+1,1); MFMA mh0 x np0
#pragma unroll
    for (int i = 0; i < 4; ++i)
#pragma unroll
      for (int ks = 0; ks < 2; ++ks)
        fa[i][ks] = *(const short8*)(Ab + (i * 16 + fr) * 64 + ((kg + ks * 4) ^ fr7) * 8);
#pragma unroll
    for (int ni = 0; ni < 2; ++ni)
#pragma unroll
      for (int ks = 0; ks < 2; ++ks)
        fb[ni][ks] = *(const short8*)(Bbp + (qh * 64 + ni * 16 + fr) * 64 + ((kg + ks * 4) ^ fr7) * 8);
    if (t + 1 < 8) STAGEH(t + 1, 1);
    BAR();
    __builtin_amdgcn_s_setprio(1);
#pragma unroll
    for (int i = 0; i < 4; ++i)
#pragma unroll
      for (int j = 0; j < 2; ++j)
#pragma unroll
        for (int ks = 0; ks < 2; ++ks)
          acc[i][j] = __builtin_amdgcn_mfma_f32_16x16x32_bf16(fa[i][ks], fb[j][ks], acc[i][j], 0, 0, 0);
    __builtin_amdgcn_s_setprio(0);
    BAR();

    // ---- phase 1: read fb(ni2-3); MFMA mh0 x np1
#pragma unroll
    for (int ni = 2; ni < 4; ++ni)
#pragma unroll
      for (int ks = 0; ks < 2; ++ks)
        fb[ni][ks] = *(const short8*)(Bbp + (qh * 64 + ni * 16 + fr) * 64 + ((kg + ks * 4) ^ fr7) * 8);
    BAR();
    __builtin_amdgcn_s_setprio(1);
#pragma unroll
    for (int i = 0; i < 4; ++i)
#pragma unroll
      for (int j = 2; j < 4; ++j)
#pragma unroll
        for (int ks = 0; ks < 2; ++ks)
          acc[i][j] = __builtin_amdgcn_mfma_f32_16x16x32_bf16(fa[i][ks], fb[j][ks], acc[i][j], 0, 0, 0);
    __builtin_amdgcn_s_setprio(0);
    BAR();

    // ---- phase 2: read fa(mi4-7); MFMA mh1 x np0
#pragma unroll
    for (int i = 0; i < 4; ++i)
#pragma unroll
      for (int ks = 0; ks < 2; ++ks)
        fa[i][ks] = *(const short8*)(Ab + ((i + 4) * 16 + fr) * 64 + ((kg + ks * 4) ^ fr7) * 8);
    BAR();
    __builtin_amdgcn_s_setprio(1);
#pragma unroll
    for (int i = 0; i < 4; ++i)
#pragma unroll
      for (int j = 0; j < 2; ++j)
#pragma unroll
        for (int ks = 0; ks < 2; ++ks)
          acc[i + 4][j] = __builtin_amdgcn_mfma_f32_16x16x32_bf16(fa[i][ks], fb[j][ks], acc[i + 4][j], 0, 0, 0);
    __builtin_amdgcn_s_setprio(0);
    BAR();

    // ---- phase 3: stage H(t+2,0) (slot(d,0) fully read at p2); MFMA mh1 x np1
    if (t + 2 < 8) STAGEH(t + 2, 0);
    BAR();
    __builtin_amdgcn_s_setprio(1);
#pragma unroll
    for (int i = 0; i < 4; ++i)
#pragma unroll
      for (int j = 2; j < 4; ++j)
#pragma unroll
        for (int ks = 0; ks < 2; ++ks)
          acc[i + 4][j] = __builtin_amdgcn_mfma_f32_16x16x32_bf16(fa[i][ks], fb[j][ks], acc[i + 4][j], 0, 0, 0);
    __builtin_amdgcn_s_setprio(0);
    // loop head does [vmcnt; BAR]
  }
#undef STAGEH

  // ---- Epilogue ----
  BAR();   // K-loop fully done for all waves; smem reusable

  // ap waves dump raw ph preacts (bf16, XOR-swizzled col-major [64][128])
  if (q >= 2) {
    char* Rb = smem + (m * 2 + (q - 2)) * 16384;
#pragma unroll
    for (int mi = 0; mi < 8; ++mi)
#pragma unroll
      for (int ni = 0; ni < 4; ++ni) {
        int r0 = mi * 16 + kg * 4;
        int cl = ni * 16 + fr;           // 0..63 local to region
        ushort4 o;
        o.x = bf16_rne(acc[mi][ni][0]);
        o.y = bf16_rne(acc[mi][ni][1]);
        o.z = bf16_rne(acc[mi][ni][2]);
        o.w = bf16_rne(acc[mi][ni][3]);
        *(ushort4*)(Rb + (((cl * 128 + r0) * 2) ^ ((cl & 7) << 4))) = o;
      }
  }
  __syncthreads();

  float* segA = (float*)(smem + 65536);   // [64][128]
  float* segH = (float*)(smem + 98304);   // [64][128]

  if (q < 2) {
    const char* Rb = smem + (m * 2 + q) * 16384;
#pragma unroll
    for (int ni = 0; ni < 4; ++ni) {
      int cl64 = ni * 16 + fr;            // col local to region
      int cl = q * 64 + cl64;             // 0..127 block h-col
      int colG = h0 + cl;
      float bzv = bz[colG], bhv = bh[colG];
#pragma unroll
      for (int mi = 0; mi < 8; ++mi) {
        int r0 = mi * 16 + kg * 4;
        ushort4 p4 = *(const ushort4*)(Rb + (((cl64 * 128 + r0) * 2) ^ ((cl64 & 7) << 4)));
        const unsigned short* pp = (const unsigned short*)&p4;
        float A4 = 1.f, H4 = 0.f;
#pragma unroll
        for (int j = 0; j < 4; ++j) {
          float a, v;
          gates_c(acc[mi][ni][j] + bzv, bf16_tof(pp[j]) + bhv, a, v);
          int rowG = row0 + m * 128 + r0 + j;
          unsigned int u = (unsigned int)__half_as_ushort(__float2half_rn(a)) |
                           ((unsigned int)__half_as_ushort(__float2half_rn(v)) << 16);
          av[(size_t)rowG * Hh + colG] = u;
          H4 = fmaf(a, H4, v);
          A4 *= a;
        }
        int srow = m * 32 + mi * 4 + kg;  // 0..63
        segA[srow * 128 + cl] = A4;
        segH[srow * 128 + cl] = H4;
      }
    }
  }
  __syncthreads();

  // fold 8 segments -> chunk (32 rows); 8 chunks x 128 cols = 1024 outputs
  const int b = row0 >> 12;
  const int cbase = (row0 & 4095) >> 5;
#pragma unroll
  for (int p0i = 0; p0i < 2; ++p0i) {
    int p = p0i * 512 + tid;
    int ch = p >> 7, cl = p & 127;
    float A = 1.f, H = 0.f;
#pragma unroll
    for (int s = 0; s < 8; ++s) {
      int srow = ch * 8 + s;
      float As = segA[srow * 128 + cl];
      float Hs = segH[srow * 128 + cl];
      H = fmaf(As, H, Hs);
      A *= As;
    }
    size_t idx = ((size_t)b * CHUNKS + cbase + ch) * Hh + h0 + cl;
    aggA[idx] = A;
    aggH[idx] = H;
  }
}

// ---------- R9 fallback (reg-staged, used only if ws too small for xb) ----------
__global__ __launch_bounds__(256, 2) void gemm_fused_fb(
    const float* __restrict__ x, const unsigned short* __restrict__ Wc,
    const float* __restrict__ bz, const float* __restrict__ bh,
    unsigned int* __restrict__ av,
    float* __restrict__ aggA, float* __restrict__ aggH) {
  __shared__ __align__(16) char smem[49152];
  unsigned short* Abf = (unsigned short*)smem;
  unsigned short* Bzf = (unsigned short*)(smem + 16384);
  unsigned short* Bhf = (unsigned short*)(smem + 32768);
  float* AsL = (float*)smem;
  float* HsL = (float*)(smem + 16384);

  const int tid = threadIdx.x;
  const int lane = tid & 63, wid = tid >> 6;
  int swz = (blockIdx.x & 7) * 128 + (blockIdx.x >> 3);
  const int bm = swz >> 2, hn = swz & 3;
  const int row0 = bm * 128, h0 = hn * 128;
  const int wr = (wid >> 1) * 64, hc = (wid & 1) * 64;
  const int fr = lane & 15, kg = lane >> 4;
  const int r8 = lane >> 3;
  const int c8 = ((lane & 7) ^ r8) * 8;
  const int fr7 = lane & 7;
  const int sk0 = (kg ^ fr7) * 8;
  const int sk1 = ((kg + 4) ^ fr7) * 8;

  f32x4 ak[4][4], ap[4][4];
#pragma unroll
  for (int i = 0; i < 4; ++i)
#pragma unroll
    for (int j = 0; j < 4; ++j) { ak[i][j] = (f32x4)0.f; ap[i][j] = (f32x4)0.f; }

  for (int k0 = 0; k0 < Dd; k0 += 64) {
    float4 avx[8];
#pragma unroll
    for (int i = 0; i < 8; ++i) {
      int f = i * 256 + tid;
      avx[i] = *(const float4*)(x + (size_t)(row0 + (f >> 4)) * Dd + k0 + (f & 15) * 4);
    }
    __syncthreads();
#pragma unroll
    for (int i = 0; i < 4; ++i) {
      int rw = wid * 32 + i * 8;
      gload_lds16(Wc + (size_t)(h0 + rw + r8) * Dd + k0 + c8, &Bzf[rw * 64]);
      gload_lds16(Wc + (size_t)(512 + h0 + rw + r8) * Dd + k0 + c8, &Bhf[rw * 64]);
    }
#pragma unroll
    for (int i = 0; i < 8; ++i) {
      int f = i * 256 + tid;
      int r = f >> 4;
      uint2 hv = pack4_bf16((const float*)&avx[i]);
      int soff = ((((f & 15) >> 1) ^ (r & 7)) * 8) + (f & 1) * 4;
      *(uint2*)&Abf[r * 64 + soff] = hv;
    }
    __syncthreads();
#pragma unroll
    for (int ks = 0; ks < 2; ++ks) {
      const int sk = ks ? sk1 : sk0;
      short8 fa[4], fz[4], fh[4];
#pragma unroll
      for (int mi = 0; mi < 4; ++mi)
        fa[mi] = *(const short8*)&Abf[(wr + mi * 16 + fr) * 64 + sk];
#pragma unroll
      for (int ni = 0; ni < 4; ++ni) {
        fz[ni] = *(const short8*)&Bzf[(hc + ni * 16 + fr) * 64 + sk];
        fh[ni] = *(const short8*)&Bhf[(hc + ni * 16 + fr) * 64 + sk];
      }
#pragma unroll
      for (int mi = 0; mi < 4; ++mi)
#pragma unroll
        for (int ni = 0; ni < 4; ++ni) {
          ak[mi][ni] = __builtin_amdgcn_mfma_f32_16x16x32_bf16(fa[mi], fz[ni], ak[mi][ni], 0, 0, 0);
          ap[mi][ni] = __builtin_amdgcn_mfma_f32_16x16x32_bf16(fa[mi], fh[ni], ap[mi][ni], 0, 0, 0);
        }
    }
    __syncthreads();
  }

#pragma unroll
  for (int ni = 0; ni < 4; ++ni) {
    int colG = h0 + hc + ni * 16 + fr;
    float bzv = bz[colG], bhv = bh[colG];
    int cl = hc + ni * 16 + fr;
#pragma unroll
    for (int mi = 0; mi < 4; ++mi) {
      float A4 = 1.f, H4 = 0.f;
#pragma unroll
      for (int j = 0; j < 4; ++j) {
        float a, v;
        gates_c(ak[mi][ni][j] + bzv, ap[mi][ni][j] + bhv, a, v);
        int row = row0 + wr + mi * 16 + kg * 4 + j;
        unsigned int u = (unsigned int)__half_as_ushort(__float2half_rn(a)) |
                         ((unsigned int)__half_as_ushort(__float2half_rn(v)) << 16);
        av[(size_t)row * Hh + colG] = u;
        H4 = fmaf(a, H4, v);
        A4 *= a;
      }
      int srow = (wr >> 2) + mi * 4 + kg;
      AsL[srow * 128 + cl] = A4;
      HsL[srow * 128 + cl] = H4;
    }
  }
  __syncthreads();
  const int b = row0 >> 12;
  const int cbase = (row0 & 4095) >> 5;
#pragma unroll
  for (int p0i = 0; p0i < 2; ++p0i) {
    int p = p0i * 256 + tid;
    int ch = p >> 7, cl = p & 127;
    float A = 1.f, H = 0.f;
#pragma unroll
    for (int s = 0; s < 8; ++s) {
      int srow = ch * 8 + s;
      float As = AsL[srow * 128 + cl];
      float Hs = HsL[srow * 128 + cl];
      H = fmaf(As, H, Hs);
      A *= As;
    }
    size_t idx = ((size_t)b * CHUNKS + cbase + ch) * Hh + h0 + cl;
    aggA[idx] = A;
    aggH[idx] = H;
  }
}

// Kogge-Stone scan over chunk aggregates (affine composition).
__global__ __launch_bounds__(256) void scan_carry_ks(
    const float* __restrict__ aggA, const float* __restrict__ aggH,
    const float* __restrict__ h0, float* __restrict__ carry) {
  __shared__ float As[256], Hs[256];
  const int tid = threadIdx.x;
  const int c = tid & 127;
  const int gch = blockIdx.x * 2 + (tid >> 7);
  const int b = gch >> 9, h = gch & 511;
  size_t base = (size_t)b * CHUNKS * Hh + h;
  float A = aggA[base + (size_t)c * Hh];
  float H = aggH[base + (size_t)c * Hh];
  As[tid] = A; Hs[tid] = H;
  __syncthreads();
#pragma unroll
  for (int s = 1; s < 128; s <<= 1) {
    float Al = 1.f, Hl = 0.f;
    const bool act = (c >= s);
    if (act) { Al = As[tid - s]; Hl = Hs[tid - s]; }
    __syncthreads();
    if (act) {
      H = fmaf(A, Hl, H);
      A = A * Al;
      As[tid] = A; Hs[tid] = H;
    }
    __syncthreads();
  }
  float hv = h0[(size_t)b * Hh + h];
  float g0 = (hv >= 0.f) ? (hv + 0.5f) : 1.f / (1.f + __expf(-hv));
  float cr;
  if (c == 0) cr = g0;
  else cr = fmaf(As[tid - 1], g0, Hs[tid - 1]);
  carry[base + (size_t)c * Hh] = cr;
}

// Apply carry: read packed (a,v), write final h (fp32) to d_out.
__global__ __launch_bounds__(512) void scan_apply_av(
    const unsigned int* __restrict__ av, const float* __restrict__ carry,
    float* __restrict__ out) {
  const int h = threadIdx.x;
  const int bc = blockIdx.x;
  const int b = bc >> 7, c = bc & 127;
  float hp = carry[(size_t)bc * Hh + h];
  size_t base = ((size_t)b * Tt + (size_t)c * CLEN) * Hh + h;
#pragma unroll
  for (int i = 0; i < CLEN; ++i) {
    size_t idx = base + (size_t)i * Hh;
    unsigned int u = av[idx];
    float a = __half2float(__ushort_as_half((unsigned short)(u & 0xFFFFu)));
    float v = __half2float(__ushort_as_half((unsigned short)(u >> 16)));
    hp = fmaf(a, hp, v);
    out[idx] = hp;
  }
}

extern "C" void kernel_launch(void* const* d_in, const int* in_sizes, int n_in,
                              void* d_out, int out_size, void* d_ws, size_t ws_size,
                              hipStream_t stream) {
  const float* x  = (const float*)d_in[0];
  const float* h0 = (const float*)d_in[1];
  const float* Wz = (const float*)d_in[2];
  const float* bz = (const float*)d_in[3];
  const float* Wh = (const float*)d_in[4];
  const float* bh = (const float*)d_in[5];
  float* out = (float*)d_out;

  char* w = (char*)d_ws;
  unsigned int* avb    = (unsigned int*)w;                 // 64 MB packed (a,v)
  unsigned short* Wc   = (unsigned short*)(w + 67108864);  // 1 MB
  float* aggA          = (float*)(w + 68157440);           // 2 MB
  float* aggH          = (float*)(w + 70254592);           // 2 MB
  float* carry         = (float*)(w + 72351744);           // 2 MB (end 74448896)
  unsigned short* xb   = (unsigned short*)(w + 74448896);  // 32 MB (end 108003328)
  const bool useXB = ws_size >= 108003328ull;

  if (useXB) {
    prep_all<<<16896, 256, 0, stream>>>(x, Wz, Wh, xb, Wc);
    gemm8<<<(Mm / 256) * (Hh / 128), 512, 0, stream>>>(xb, Wc, bz, bh, avb, aggA, aggH);
  } else {
    prep_w<<<512, 256, 0, stream>>>(Wz, Wh, Wc);
    gemm_fused_fb<<<(Mm / 128) * (Hh / 128), 256, 0, stream>>>(x, Wc, bz, bh, avb, aggA, aggH);
  }
  scan_carry_ks<<<(Bb * Hh) / 2, 256, 0, stream>>>(aggA, aggH, h0, carry);
  scan_apply_av<<<Bb * CHUNKS, 512, 0, stream>>>(avb, carry, out);
}